// Round 10
// baseline (1590.733 us; speedup 1.0000x reference)
//
#include <hip/hip_runtime.h>
#include <hip/hip_fp16.h>

#define DIM 128
#define NPB 256        // nodes per bucket
#define BCAP 5120      // bucket capacity (mean 4092, +16 sigma)
#define T_SCAT 4096

typedef _Float16 half8 __attribute__((ext_vector_type(8)));
typedef float floatx4 __attribute__((ext_vector_type(4)));
typedef float floatx2 __attribute__((ext_vector_type(2)));

// ---------------- shared gemm block body: 64 nodes -> A fp8 ----------------
__device__ __forceinline__ void gemm_block(const float* __restrict__ X,
                                           const __half* __restrict__ w1frag,
                                           unsigned char* __restrict__ A,
                                           int N, int gb) {
    const int t = threadIdx.x;
    const int w = t >> 6, l = t & 63;
    const int q = l >> 4;
    const int node = gb * 64 + w * 16 + (l & 15);
    const bool valid = node < N;
    half8 bfrag[4];
#pragma unroll
    for (int ks = 0; ks < 4; ks++) {
        float4 f0 = make_float4(0, 0, 0, 0), f1 = make_float4(0, 0, 0, 0);
        if (valid) {
            const float* px = X + (size_t)node * DIM + ks * 32 + q * 8;
            f0 = *(const float4*)px;
            f1 = *(const float4*)(px + 4);
        }
        bfrag[ks][0] = (_Float16)f0.x; bfrag[ks][1] = (_Float16)f0.y;
        bfrag[ks][2] = (_Float16)f0.z; bfrag[ks][3] = (_Float16)f0.w;
        bfrag[ks][4] = (_Float16)f1.x; bfrag[ks][5] = (_Float16)f1.y;
        bfrag[ks][6] = (_Float16)f1.z; bfrag[ks][7] = (_Float16)f1.w;
    }
    const half8* wf = (const half8*)w1frag;
#pragma unroll
    for (int ct = 0; ct < 8; ct++) {
        floatx4 acc = {0.f, 0.f, 0.f, 0.f};
#pragma unroll
        for (int ks = 0; ks < 4; ks++) {
            half8 afrag = wf[(ct * 4 + ks) * 64 + l];
            acc = __builtin_amdgcn_mfma_f32_16x16x32_f16(afrag, bfrag[ks], acc, 0, 0, 0);
        }
        if (valid) {
            int st = 0;
            st = __builtin_amdgcn_cvt_pk_fp8_f32(acc[0], acc[1], st, false);
            st = __builtin_amdgcn_cvt_pk_fp8_f32(acc[2], acc[3], st, true);
            *(int*)(A + (size_t)node * DIM + ct * 16 + q * 4) = st;
        }
    }
}

// ---------------- L1 prep: w1frag, w2o, cbuf, zero bcur ----------------
__global__ void prep_k(const float* __restrict__ W1, const float* __restrict__ W2,
                       const float* __restrict__ Wo, const float* __restrict__ b2,
                       const float* __restrict__ bo,
                       __half* __restrict__ w1frag, float* __restrict__ w2o,
                       float* __restrict__ cbuf, int* __restrict__ bcur) {
    if (blockIdx.x < 8) {
        int idx = blockIdx.x * 256 + threadIdx.x;   // 0..2047
        int ct = idx >> 8, ks = (idx >> 6) & 3, l = idx & 63;
        int m = l & 15, q = l >> 4;
        half8 vals;
#pragma unroll
        for (int j = 0; j < 8; j++)
            vals[j] = (_Float16)W1[(ks * 32 + q * 8 + j) * DIM + ct * 16 + m];
        ((half8*)w1frag)[idx] = vals;
    } else if (blockIdx.x == 8) {
        int t = threadIdx.x;
        if (t < 128) {
            float s = 0.f;
            for (int k = 0; k < 128; k++) s += W2[t * 128 + k] * Wo[k];
            w2o[t] = s;
        }
        if (t == 0) {
            float c = bo[0];
            for (int k = 0; k < 128; k++) c += b2[k] * Wo[k];
            cbuf[0] = c;
        }
    } else {
#pragma unroll
        for (int i = 0; i < 4; i++) bcur[threadIdx.x + i * 256] = 0;
    }
}

// ---------------- L2: bscatter (two-pass, R8-proven) + ALL gemm ----------------
// bucket b = dst >> 8; bucket b owns [b*BCAP, (b+1)*BCAP) in be.
__global__ __launch_bounds__(256) void scatter_gemm_k(
        const int* __restrict__ ei, int E, int ntiles,
        int2* __restrict__ be, int* __restrict__ bcur,
        const float* __restrict__ X, const __half* __restrict__ w1frag,
        unsigned char* __restrict__ A, int N) {
    if (blockIdx.x >= (unsigned)ntiles) {
        gemm_block(X, w1frag, A, N, blockIdx.x - ntiles);
        return;
    }
    __shared__ int lcnt[1024];
    __shared__ int lscan[1024];
    __shared__ int lbase[1024];
    __shared__ int wsum[4];
    __shared__ int2 stage[T_SCAT];
    const int t = threadIdx.x;
    const int lane = t & 63, w = t >> 6;
    const int tile0 = blockIdx.x * T_SCAT;
    int tcnt = E - tile0; if (tcnt > T_SCAT) tcnt = T_SCAT;
    for (int i = t; i < 1024; i += 256) lcnt[i] = 0;
    __syncthreads();
    // pass A: bucket histogram
    for (int i = t; i < tcnt; i += 256)
        atomicAdd(&lcnt[ei[E + tile0 + i] >> 8], 1);
    __syncthreads();
    // scan 1024 counts (4/thread, shfl wave-scan); reserve global bucket space
    const int b4 = t * 4;
    int c0 = lcnt[b4], c1 = lcnt[b4 + 1], c2 = lcnt[b4 + 2], c3 = lcnt[b4 + 3];
    int s4 = c0 + c1 + c2 + c3;
    int v = s4;
#pragma unroll
    for (int off = 1; off < 64; off <<= 1) {
        int u = __shfl_up(v, off, 64);
        if (lane >= off) v += u;
    }
    if (lane == 63) wsum[w] = v;
    __syncthreads();
    int wbase = 0;
#pragma unroll
    for (int i = 0; i < 4; i++) wbase += (i < w) ? wsum[i] : 0;
    int run = wbase + v - s4;
    lscan[b4] = run;
    if (c0) lbase[b4] = b4 * BCAP + atomicAdd(&bcur[b4], c0);
    run += c0; lscan[b4 + 1] = run;
    if (c1) lbase[b4 + 1] = (b4 + 1) * BCAP + atomicAdd(&bcur[b4 + 1], c1);
    run += c1; lscan[b4 + 2] = run;
    if (c2) lbase[b4 + 2] = (b4 + 2) * BCAP + atomicAdd(&bcur[b4 + 2], c2);
    run += c2; lscan[b4 + 3] = run;
    if (c3) lbase[b4 + 3] = (b4 + 3) * BCAP + atomicAdd(&bcur[b4 + 3], c3);
    lcnt[b4] = 0; lcnt[b4 + 1] = 0; lcnt[b4 + 2] = 0; lcnt[b4 + 3] = 0;
    __syncthreads();
    // pass B: re-read (L2-hot), rank, stage
    for (int i = t; i < tcnt; i += 256) {
        int s = ei[tile0 + i];
        int d = ei[E + tile0 + i];
        int b = d >> 8;
        int r = atomicAdd(&lcnt[b], 1);
        stage[lscan[b] + r] = make_int2(s, d);
    }
    __syncthreads();
    // contiguous-run copy out (~10.5-edge runs)
    for (int i = t; i < tcnt; i += 256) {
        int2 ed = stage[i];
        int b = ed.y >> 8;
        be[lbase[b] + (i - lscan[b])] = ed;
    }
}

// ---------------- L3: per-bucket degree histogram -> dinv ----------------
__global__ __launch_bounds__(256) void deg_k(const int2* __restrict__ be,
                                             const int* __restrict__ bcur,
                                             float* __restrict__ dinv, int N) {
    __shared__ int lcnt[256];
    const int t = threadIdx.x, b = blockIdx.x, s = b * BCAP;
    int cnt = bcur[b]; if (cnt > BCAP) cnt = BCAP;
    lcnt[t] = 0;
    __syncthreads();
    for (int i = t; i < cnt; i += 256)
        atomicAdd(&lcnt[be[s + i].y & 255], 1);
    __syncthreads();
    int node = b * NPB + t;
    if (node < N) dinv[node] = rsqrtf((float)lcnt[t] + 1.0f);
}

__device__ __forceinline__ void dec8(int2 r, float* f) {
    floatx2 a = __builtin_amdgcn_cvt_pk_f32_fp8(r.x, false);
    floatx2 b = __builtin_amdgcn_cvt_pk_f32_fp8(r.x, true);
    floatx2 c = __builtin_amdgcn_cvt_pk_f32_fp8(r.y, false);
    floatx2 d = __builtin_amdgcn_cvt_pk_f32_fp8(r.y, true);
    f[0] = a[0]; f[1] = a[1]; f[2] = b[0]; f[3] = b[1];
    f[4] = c[0]; f[5] = c[1]; f[6] = d[0]; f[7] = d[1];
}

// ---------------- L4: sort-free aggregation via LDS fp32 accumulators ----------------
// Grid = 2*NB: block handles bucket = blockIdx>>1, half = blockIdx&1 (128 nodes).
// acc[dl][slot]: float j of a row stored at slot = (j%8)*16 + (j/8)  (4-way ds_add banks).
// acc accumulates sum_{s in nbrs ∪ {n}} dinv[s]*h[s]; epilogue: zp[n] = dn*dot(relu(dn*acc+b1),w2o).
__global__ __launch_bounds__(1024) void agg_k(
        const int2* __restrict__ be, const int* __restrict__ bcur,
        const float* __restrict__ dinv, const unsigned char* __restrict__ A,
        const float* __restrict__ b1, const float* __restrict__ w2o,
        float* __restrict__ zp, int N) {
    __shared__ float acc[128 * DIM];   // 64 KB
    const int t = threadIdx.x;
    const int bkt = blockIdx.x >> 1;
    const int half = blockIdx.x & 1;
    const int s0 = bkt * BCAP;
    int cnt = bcur[bkt]; if (cnt > BCAP) cnt = BCAP;
    for (int i = t; i < 128 * DIM; i += 1024) acc[i] = 0.f;
    __syncthreads();
    const int li = t & 15, sg = t >> 4;   // 64 subgroups of 16 lanes
    const int items = 128 + cnt;          // 128 virtual self-edges + real edges
    for (int w = sg; w < items; w += 64) {
        int s, dl;
        if (w < 128) {
            s = bkt * NPB + half * 128 + w;
            dl = w;
            if (s >= N) continue;
        } else {
            int2 ed = be[s0 + w - 128];
            int d255 = ed.y & 255;
            if ((d255 >> 7) != half) continue;
            s = ed.x; dl = d255 & 127;
        }
        float ws = dinv[s];
        int2 hraw = *(const int2*)(A + (size_t)s * DIM + li * 8);
        float h[8]; dec8(hraw, h);
        float* arow = &acc[dl * DIM];
#pragma unroll
        for (int k = 0; k < 8; k++)
            atomicAdd(&arow[k * 16 + li], ws * h[k]);
    }
    __syncthreads();
    // epilogue: 8 threads per node, 16 slots each
    const int nn = t >> 3, q8 = t & 7;
    const int node = bkt * NPB + half * 128 + nn;
    if (node < N) {
        float dn = dinv[node];
        float sum = 0.f;
        const float* arow = &acc[nn * DIM];
#pragma unroll
        for (int u = 0; u < 16; u++) {
            int m = q8 * 16 + u;
            int j = 8 * (m & 15) + (m >> 4);   // inverse of slot swizzle
            sum += fmaxf(fmaf(dn, arow[m], b1[j]), 0.f) * w2o[j];
        }
        sum += __shfl_xor(sum, 1, 64);
        sum += __shfl_xor(sum, 2, 64);
        sum += __shfl_xor(sum, 4, 64);
        if (q8 == 0) zp[node] = dn * sum;   // zp = dinv*z
    }
}

// ---------------- L5: final via LDS scalar accumulation ----------------
// out[n] = dn*(sum_{s in nbrs} zp[s] + zp[n]) + c     (zp = dinv*z)
__global__ __launch_bounds__(256) void final_k(
        const int2* __restrict__ be, const int* __restrict__ bcur,
        const float* __restrict__ dinv, const float* __restrict__ zp,
        const float* __restrict__ cbuf, float* __restrict__ out, int N) {
    __shared__ float zacc[NPB];
    const int t = threadIdx.x, b = blockIdx.x, s0 = b * BCAP;
    int cnt = bcur[b]; if (cnt > BCAP) cnt = BCAP;
    zacc[t] = 0.f;
    __syncthreads();
    for (int i = t; i < cnt; i += 256) {
        int2 ed = be[s0 + i];
        atomicAdd(&zacc[ed.y & 255], zp[ed.x]);
    }
    __syncthreads();
    int node = b * NPB + t;
    if (node < N) {
        float dn = dinv[node];
        out[node] = fmaf(dn, zacc[t] + zp[node], cbuf[0]);
    }
}

extern "C" void kernel_launch(void* const* d_in, const int* in_sizes, int n_in,
                              void* d_out, int out_size, void* d_ws, size_t ws_size,
                              hipStream_t stream) {
    const float* x  = (const float*)d_in[0];
    const int*   ei = (const int*)d_in[1];
    const float* W1 = (const float*)d_in[2];
    const float* b1 = (const float*)d_in[3];
    const float* W2 = (const float*)d_in[4];
    const float* b2 = (const float*)d_in[5];
    const float* Wo = (const float*)d_in[6];
    const float* bo = (const float*)d_in[7];
    float* out = (float*)d_out;

    const int N = in_sizes[0] / DIM;
    const int E = in_sizes[1] / 2;
    const int NB = (N + NPB - 1) >> 8;         // 256-node buckets
    const int ntiles = (E + T_SCAT - 1) / T_SCAT;
    const int ngemm = (N + 63) / 64;

    char* p = (char*)d_ws;
    auto alloc = [&](size_t bytes) {
        void* r = (void*)p;
        p += (bytes + 255) & ~size_t(255);
        return r;
    };
    unsigned char* A = (unsigned char*)alloc((size_t)N * DIM);          // 12.8 MB
    int2*  be     = (int2*)alloc((size_t)NB * BCAP * 8);                // 16 MB
    float* zp     = (float*)alloc((size_t)N * 4);
    float* dinv   = (float*)alloc((size_t)N * 4);
    float* w2o    = (float*)alloc(128 * 4);
    float* cbuf   = (float*)alloc(16);
    __half* w1frag= (__half*)alloc(2048 * 8 * 2);   // 32 KB
    int* bcur     = (int*)alloc(1024 * 4);

    prep_k<<<10, 256, 0, stream>>>(W1, W2, Wo, b2, bo, w1frag, w2o, cbuf, bcur);
    scatter_gemm_k<<<ntiles + ngemm, 256, 0, stream>>>(ei, E, ntiles, be, bcur,
                                                       x, w1frag, A, N);
    deg_k<<<NB, 256, 0, stream>>>(be, bcur, dinv, N);
    agg_k<<<NB * 2, 1024, 0, stream>>>(be, bcur, dinv, A, b1, w2o, zp, N);
    final_k<<<NB, 256, 0, stream>>>(be, bcur, dinv, zp, cbuf, out, N);
}

// Round 11
// 440.716 us; speedup vs baseline: 3.6094x; 3.6094x over previous
//
#include <hip/hip_runtime.h>
#include <hip/hip_fp16.h>

#define DIM 128
#define NPB 256        // nodes per bucket
#define BCAP 5120      // bucket capacity (mean 4092, +16 sigma)
#define T_SCAT 4096
#define SCALE_A 4194304.0f              // 2^22 fixed-point scale
#define INV_SCALE_A 2.384185791015625e-07f

typedef _Float16 half8 __attribute__((ext_vector_type(8)));
typedef float floatx4 __attribute__((ext_vector_type(4)));
typedef float floatx2 __attribute__((ext_vector_type(2)));

// ---------------- shared gemm block body: 64 nodes -> A fp8 ----------------
__device__ __forceinline__ void gemm_block(const float* __restrict__ X,
                                           const __half* __restrict__ w1frag,
                                           unsigned char* __restrict__ A,
                                           int N, int gb) {
    const int t = threadIdx.x;
    const int w = t >> 6, l = t & 63;
    const int q = l >> 4;
    const int node = gb * 64 + w * 16 + (l & 15);
    const bool valid = node < N;
    half8 bfrag[4];
#pragma unroll
    for (int ks = 0; ks < 4; ks++) {
        float4 f0 = make_float4(0, 0, 0, 0), f1 = make_float4(0, 0, 0, 0);
        if (valid) {
            const float* px = X + (size_t)node * DIM + ks * 32 + q * 8;
            f0 = *(const float4*)px;
            f1 = *(const float4*)(px + 4);
        }
        bfrag[ks][0] = (_Float16)f0.x; bfrag[ks][1] = (_Float16)f0.y;
        bfrag[ks][2] = (_Float16)f0.z; bfrag[ks][3] = (_Float16)f0.w;
        bfrag[ks][4] = (_Float16)f1.x; bfrag[ks][5] = (_Float16)f1.y;
        bfrag[ks][6] = (_Float16)f1.z; bfrag[ks][7] = (_Float16)f1.w;
    }
    const half8* wf = (const half8*)w1frag;
#pragma unroll
    for (int ct = 0; ct < 8; ct++) {
        floatx4 acc = {0.f, 0.f, 0.f, 0.f};
#pragma unroll
        for (int ks = 0; ks < 4; ks++) {
            half8 afrag = wf[(ct * 4 + ks) * 64 + l];
            acc = __builtin_amdgcn_mfma_f32_16x16x32_f16(afrag, bfrag[ks], acc, 0, 0, 0);
        }
        if (valid) {
            int st = 0;
            st = __builtin_amdgcn_cvt_pk_fp8_f32(acc[0], acc[1], st, false);
            st = __builtin_amdgcn_cvt_pk_fp8_f32(acc[2], acc[3], st, true);
            *(int*)(A + (size_t)node * DIM + ct * 16 + q * 4) = st;
        }
    }
}

// ---------------- L1 prep: w1frag, w2o, cbuf, zero bcur ----------------
__global__ void prep_k(const float* __restrict__ W1, const float* __restrict__ W2,
                       const float* __restrict__ Wo, const float* __restrict__ b2,
                       const float* __restrict__ bo,
                       __half* __restrict__ w1frag, float* __restrict__ w2o,
                       float* __restrict__ cbuf, int* __restrict__ bcur) {
    if (blockIdx.x < 8) {
        int idx = blockIdx.x * 256 + threadIdx.x;   // 0..2047
        int ct = idx >> 8, ks = (idx >> 6) & 3, l = idx & 63;
        int m = l & 15, q = l >> 4;
        half8 vals;
#pragma unroll
        for (int j = 0; j < 8; j++)
            vals[j] = (_Float16)W1[(ks * 32 + q * 8 + j) * DIM + ct * 16 + m];
        ((half8*)w1frag)[idx] = vals;
    } else if (blockIdx.x == 8) {
        int t = threadIdx.x;
        if (t < 128) {
            float s = 0.f;
            for (int k = 0; k < 128; k++) s += W2[t * 128 + k] * Wo[k];
            w2o[t] = s;
        }
        if (t == 0) {
            float c = bo[0];
            for (int k = 0; k < 128; k++) c += b2[k] * Wo[k];
            cbuf[0] = c;
        }
    } else {
#pragma unroll
        for (int i = 0; i < 4; i++) bcur[threadIdx.x + i * 256] = 0;
    }
}

// ---------------- L2: bscatter (two-pass, R8-proven) + ALL gemm ----------------
__global__ __launch_bounds__(256) void scatter_gemm_k(
        const int* __restrict__ ei, int E, int ntiles,
        int2* __restrict__ be, int* __restrict__ bcur,
        const float* __restrict__ X, const __half* __restrict__ w1frag,
        unsigned char* __restrict__ A, int N) {
    if (blockIdx.x >= (unsigned)ntiles) {
        gemm_block(X, w1frag, A, N, blockIdx.x - ntiles);
        return;
    }
    __shared__ int lcnt[1024];
    __shared__ int lscan[1024];
    __shared__ int lbase[1024];
    __shared__ int wsum[4];
    __shared__ int2 stage[T_SCAT];
    const int t = threadIdx.x;
    const int lane = t & 63, w = t >> 6;
    const int tile0 = blockIdx.x * T_SCAT;
    int tcnt = E - tile0; if (tcnt > T_SCAT) tcnt = T_SCAT;
    for (int i = t; i < 1024; i += 256) lcnt[i] = 0;
    __syncthreads();
    for (int i = t; i < tcnt; i += 256)
        atomicAdd(&lcnt[ei[E + tile0 + i] >> 8], 1);
    __syncthreads();
    const int b4 = t * 4;
    int c0 = lcnt[b4], c1 = lcnt[b4 + 1], c2 = lcnt[b4 + 2], c3 = lcnt[b4 + 3];
    int s4 = c0 + c1 + c2 + c3;
    int v = s4;
#pragma unroll
    for (int off = 1; off < 64; off <<= 1) {
        int u = __shfl_up(v, off, 64);
        if (lane >= off) v += u;
    }
    if (lane == 63) wsum[w] = v;
    __syncthreads();
    int wbase = 0;
#pragma unroll
    for (int i = 0; i < 4; i++) wbase += (i < w) ? wsum[i] : 0;
    int run = wbase + v - s4;
    lscan[b4] = run;
    if (c0) lbase[b4] = b4 * BCAP + atomicAdd(&bcur[b4], c0);
    run += c0; lscan[b4 + 1] = run;
    if (c1) lbase[b4 + 1] = (b4 + 1) * BCAP + atomicAdd(&bcur[b4 + 1], c1);
    run += c1; lscan[b4 + 2] = run;
    if (c2) lbase[b4 + 2] = (b4 + 2) * BCAP + atomicAdd(&bcur[b4 + 2], c2);
    run += c2; lscan[b4 + 3] = run;
    if (c3) lbase[b4 + 3] = (b4 + 3) * BCAP + atomicAdd(&bcur[b4 + 3], c3);
    lcnt[b4] = 0; lcnt[b4 + 1] = 0; lcnt[b4 + 2] = 0; lcnt[b4 + 3] = 0;
    __syncthreads();
    for (int i = t; i < tcnt; i += 256) {
        int s = ei[tile0 + i];
        int d = ei[E + tile0 + i];
        int b = d >> 8;
        int r = atomicAdd(&lcnt[b], 1);
        stage[lscan[b] + r] = make_int2(s, d);
    }
    __syncthreads();
    for (int i = t; i < tcnt; i += 256) {
        int2 ed = stage[i];
        int b = ed.y >> 8;
        be[lbase[b] + (i - lscan[b])] = ed;
    }
}

// ---------------- L3: per-bucket degree histogram -> dinv ----------------
__global__ __launch_bounds__(256) void deg_k(const int2* __restrict__ be,
                                             const int* __restrict__ bcur,
                                             float* __restrict__ dinv, int N) {
    __shared__ int lcnt[256];
    const int t = threadIdx.x, b = blockIdx.x, s = b * BCAP;
    int cnt = bcur[b]; if (cnt > BCAP) cnt = BCAP;
    lcnt[t] = 0;
    __syncthreads();
    for (int i = t; i < cnt; i += 256)
        atomicAdd(&lcnt[be[s + i].y & 255], 1);
    __syncthreads();
    int node = b * NPB + t;
    if (node < N) dinv[node] = rsqrtf((float)lcnt[t] + 1.0f);
}

__device__ __forceinline__ void dec8(int2 r, float* f) {
    floatx2 a = __builtin_amdgcn_cvt_pk_f32_fp8(r.x, false);
    floatx2 b = __builtin_amdgcn_cvt_pk_f32_fp8(r.x, true);
    floatx2 c = __builtin_amdgcn_cvt_pk_f32_fp8(r.y, false);
    floatx2 d = __builtin_amdgcn_cvt_pk_f32_fp8(r.y, true);
    f[0] = a[0]; f[1] = a[1]; f[2] = b[0]; f[3] = b[1];
    f[4] = c[0]; f[5] = c[1]; f[6] = d[0]; f[7] = d[1];
}

// ---------------- L4: sort-free aggregation via LDS FIXED-POINT accumulators -------
// Grid = 2*NB: bucket = blockIdx>>1, half = blockIdx&1 (128 nodes, 64 KB LDS ints).
// Channel j of row dl lives at acc[dl*128 + (j%8)*16 + (j/8)], scaled by 2^22.
// Native ds_add_u32 (int) — float LDS atomicAdd is a CAS loop (R10 disaster).
__global__ __launch_bounds__(1024) void agg_k(
        const int2* __restrict__ be, const int* __restrict__ bcur,
        const float* __restrict__ dinv, const unsigned char* __restrict__ A,
        const float* __restrict__ b1, const float* __restrict__ w2o,
        float* __restrict__ zp, int N) {
    __shared__ int acc[128 * DIM];   // 64 KB
    const int t = threadIdx.x;
    const int bkt = blockIdx.x >> 1;
    const int half = blockIdx.x & 1;
    const int s0 = bkt * BCAP;
    int cnt = bcur[bkt]; if (cnt > BCAP) cnt = BCAP;
    for (int i = t; i < 128 * DIM; i += 1024) acc[i] = 0;
    __syncthreads();
    const int li = t & 15, sg = t >> 4;   // 64 subgroups of 16 lanes
    const int items = 128 + cnt;          // 128 virtual self-edges + real edges
    for (int w = sg; w < items; w += 64) {
        int s, dl;
        if (w < 128) {
            s = bkt * NPB + half * 128 + w;
            dl = w;
            if (s >= N) continue;
        } else {
            int2 ed = be[s0 + w - 128];
            int d255 = ed.y & 255;
            if ((d255 >> 7) != half) continue;
            s = ed.x; dl = d255 & 127;
        }
        float wS = dinv[s] * SCALE_A;
        int2 hraw = *(const int2*)(A + (size_t)s * DIM + li * 8);
        float h[8]; dec8(hraw, h);
        int* arow = &acc[dl * DIM];
#pragma unroll
        for (int kk = 0; kk < 8; kk++) {
            int k = (kk + li) & 7;      // stagger issue order across lanes
            atomicAdd(&arow[k * 16 + li], __float2int_rn(h[k] * wS));
        }
    }
    __syncthreads();
    // epilogue: 8 threads per node, 16 slots each
    const int nn = t >> 3, q8 = t & 7;
    const int node = bkt * NPB + half * 128 + nn;
    if (node < N) {
        float dn = dinv[node];
        float sum = 0.f;
        const int* arow = &acc[nn * DIM];
#pragma unroll
        for (int u = 0; u < 16; u++) {
            int m = q8 * 16 + u;
            int j = 8 * (m & 15) + (m >> 4);   // inverse of slot swizzle
            float a = (float)arow[m] * INV_SCALE_A;
            sum += fmaxf(fmaf(dn, a, b1[j]), 0.f) * w2o[j];
        }
        sum += __shfl_xor(sum, 1, 64);
        sum += __shfl_xor(sum, 2, 64);
        sum += __shfl_xor(sum, 4, 64);
        if (q8 == 0) zp[node] = dn * sum;   // zp = dinv*z
    }
}

// ---------------- L5: final via LDS fixed-point scalar accumulation ----------------
// out[n] = dn*(sum_{s in nbrs} zp[s] + zp[n]) + c     (zp = dinv*z)
__global__ __launch_bounds__(256) void final_k(
        const int2* __restrict__ be, const int* __restrict__ bcur,
        const float* __restrict__ dinv, const float* __restrict__ zp,
        const float* __restrict__ cbuf, float* __restrict__ out, int N) {
    __shared__ int zacc[NPB];
    const int t = threadIdx.x, b = blockIdx.x, s0 = b * BCAP;
    int cnt = bcur[b]; if (cnt > BCAP) cnt = BCAP;
    zacc[t] = 0;
    __syncthreads();
    for (int i = t; i < cnt; i += 256) {
        int2 ed = be[s0 + i];
        atomicAdd(&zacc[ed.y & 255], __float2int_rn(zp[ed.x] * SCALE_A));
    }
    __syncthreads();
    int node = b * NPB + t;
    if (node < N) {
        float dn = dinv[node];
        float za = (float)zacc[t] * INV_SCALE_A;
        out[node] = fmaf(dn, za + zp[node], cbuf[0]);
    }
}

extern "C" void kernel_launch(void* const* d_in, const int* in_sizes, int n_in,
                              void* d_out, int out_size, void* d_ws, size_t ws_size,
                              hipStream_t stream) {
    const float* x  = (const float*)d_in[0];
    const int*   ei = (const int*)d_in[1];
    const float* W1 = (const float*)d_in[2];
    const float* b1 = (const float*)d_in[3];
    const float* W2 = (const float*)d_in[4];
    const float* b2 = (const float*)d_in[5];
    const float* Wo = (const float*)d_in[6];
    const float* bo = (const float*)d_in[7];
    float* out = (float*)d_out;

    const int N = in_sizes[0] / DIM;
    const int E = in_sizes[1] / 2;
    const int NB = (N + NPB - 1) >> 8;         // 256-node buckets
    const int ntiles = (E + T_SCAT - 1) / T_SCAT;
    const int ngemm = (N + 63) / 64;

    char* p = (char*)d_ws;
    auto alloc = [&](size_t bytes) {
        void* r = (void*)p;
        p += (bytes + 255) & ~size_t(255);
        return r;
    };
    unsigned char* A = (unsigned char*)alloc((size_t)N * DIM);          // 12.8 MB
    int2*  be     = (int2*)alloc((size_t)NB * BCAP * 8);                // 16 MB
    float* zp     = (float*)alloc((size_t)N * 4);
    float* dinv   = (float*)alloc((size_t)N * 4);
    float* w2o    = (float*)alloc(128 * 4);
    float* cbuf   = (float*)alloc(16);
    __half* w1frag= (__half*)alloc(2048 * 8 * 2);   // 32 KB
    int* bcur     = (int*)alloc(1024 * 4);

    prep_k<<<10, 256, 0, stream>>>(W1, W2, Wo, b2, bo, w1frag, w2o, cbuf, bcur);
    scatter_gemm_k<<<ntiles + ngemm, 256, 0, stream>>>(ei, E, ntiles, be, bcur,
                                                       x, w1frag, A, N);
    deg_k<<<NB, 256, 0, stream>>>(be, bcur, dinv, N);
    agg_k<<<NB * 2, 1024, 0, stream>>>(be, bcur, dinv, A, b1, w2o, zp, N);
    final_k<<<NB, 256, 0, stream>>>(be, bcur, dinv, zp, cbuf, out, N);
}

// Round 12
// 219.978 us; speedup vs baseline: 7.2313x; 2.0035x over previous
//
#include <hip/hip_runtime.h>
#include <hip/hip_fp16.h>

#define DIM 128
#define NPB 256        // nodes per bucket
#define BCAP 5120      // bucket capacity (mean 4092, +16 sigma)
#define T_SCAT 4096

typedef _Float16 half8 __attribute__((ext_vector_type(8)));
typedef float floatx4 __attribute__((ext_vector_type(4)));
typedef float floatx2 __attribute__((ext_vector_type(2)));

// ---------------- shared gemm block body: 64 nodes -> A fp8 ----------------
__device__ __forceinline__ void gemm_block(const float* __restrict__ X,
                                           const __half* __restrict__ w1frag,
                                           unsigned char* __restrict__ A,
                                           int N, int gb) {
    const int t = threadIdx.x;
    const int w = t >> 6, l = t & 63;
    const int q = l >> 4;
    const int node = gb * 64 + w * 16 + (l & 15);
    const bool valid = node < N;
    half8 bfrag[4];
#pragma unroll
    for (int ks = 0; ks < 4; ks++) {
        float4 f0 = make_float4(0, 0, 0, 0), f1 = make_float4(0, 0, 0, 0);
        if (valid) {
            const float* px = X + (size_t)node * DIM + ks * 32 + q * 8;
            f0 = *(const float4*)px;
            f1 = *(const float4*)(px + 4);
        }
        bfrag[ks][0] = (_Float16)f0.x; bfrag[ks][1] = (_Float16)f0.y;
        bfrag[ks][2] = (_Float16)f0.z; bfrag[ks][3] = (_Float16)f0.w;
        bfrag[ks][4] = (_Float16)f1.x; bfrag[ks][5] = (_Float16)f1.y;
        bfrag[ks][6] = (_Float16)f1.z; bfrag[ks][7] = (_Float16)f1.w;
    }
    const half8* wf = (const half8*)w1frag;
#pragma unroll
    for (int ct = 0; ct < 8; ct++) {
        floatx4 acc = {0.f, 0.f, 0.f, 0.f};
#pragma unroll
        for (int ks = 0; ks < 4; ks++) {
            half8 afrag = wf[(ct * 4 + ks) * 64 + l];
            acc = __builtin_amdgcn_mfma_f32_16x16x32_f16(afrag, bfrag[ks], acc, 0, 0, 0);
        }
        if (valid) {
            int st = 0;
            st = __builtin_amdgcn_cvt_pk_fp8_f32(acc[0], acc[1], st, false);
            st = __builtin_amdgcn_cvt_pk_fp8_f32(acc[2], acc[3], st, true);
            *(int*)(A + (size_t)node * DIM + ct * 16 + q * 4) = st;
        }
    }
}

// ---------------- L1 prep: w1frag, w2o, cbuf, zero bcur ----------------
__global__ void prep_k(const float* __restrict__ W1, const float* __restrict__ W2,
                       const float* __restrict__ Wo, const float* __restrict__ b2,
                       const float* __restrict__ bo,
                       __half* __restrict__ w1frag, float* __restrict__ w2o,
                       float* __restrict__ cbuf, int* __restrict__ bcur) {
    if (blockIdx.x < 8) {
        int idx = blockIdx.x * 256 + threadIdx.x;   // 0..2047
        int ct = idx >> 8, ks = (idx >> 6) & 3, l = idx & 63;
        int m = l & 15, q = l >> 4;
        half8 vals;
#pragma unroll
        for (int j = 0; j < 8; j++)
            vals[j] = (_Float16)W1[(ks * 32 + q * 8 + j) * DIM + ct * 16 + m];
        ((half8*)w1frag)[idx] = vals;
    } else if (blockIdx.x == 8) {
        int t = threadIdx.x;
        if (t < 128) {
            float s = 0.f;
            for (int k = 0; k < 128; k++) s += W2[t * 128 + k] * Wo[k];
            w2o[t] = s;
        }
        if (t == 0) {
            float c = bo[0];
            for (int k = 0; k < 128; k++) c += b2[k] * Wo[k];
            cbuf[0] = c;
        }
    } else {
#pragma unroll
        for (int i = 0; i < 4; i++) bcur[threadIdx.x + i * 256] = 0;
    }
}

// ---------------- L2: bscatter (two-pass, 4x/2x load batching) + ALL gemm ----------
// bucket b = dst >> 8; bucket b owns [b*BCAP, (b+1)*BCAP) in be and csr.
__global__ __launch_bounds__(256) void scatter_gemm_k(
        const int* __restrict__ ei, int E, int ntiles,
        int2* __restrict__ be, int* __restrict__ bcur,
        const float* __restrict__ X, const __half* __restrict__ w1frag,
        unsigned char* __restrict__ A, int N) {
    if (blockIdx.x >= (unsigned)ntiles) {
        gemm_block(X, w1frag, A, N, blockIdx.x - ntiles);
        return;
    }
    __shared__ int lcnt[1024];
    __shared__ int lscan[1024];
    __shared__ int lbase[1024];
    __shared__ int wsum[4];
    __shared__ int2 stage[T_SCAT];
    const int t = threadIdx.x;
    const int lane = t & 63, w = t >> 6;
    const int tile0 = blockIdx.x * T_SCAT;
    int tcnt = E - tile0; if (tcnt > T_SCAT) tcnt = T_SCAT;
    for (int i = t; i < 1024; i += 256) lcnt[i] = 0;
    __syncthreads();
    // pass A: histogram (4 loads in flight)
    for (int base = 0; base < tcnt; base += 1024) {
        int i0 = base + t;
        int d0 = -1, d1 = -1, d2 = -1, d3 = -1;
        if (i0       < tcnt) d0 = ei[E + tile0 + i0];
        if (i0 + 256 < tcnt) d1 = ei[E + tile0 + i0 + 256];
        if (i0 + 512 < tcnt) d2 = ei[E + tile0 + i0 + 512];
        if (i0 + 768 < tcnt) d3 = ei[E + tile0 + i0 + 768];
        if (d0 >= 0) atomicAdd(&lcnt[d0 >> 8], 1);
        if (d1 >= 0) atomicAdd(&lcnt[d1 >> 8], 1);
        if (d2 >= 0) atomicAdd(&lcnt[d2 >> 8], 1);
        if (d3 >= 0) atomicAdd(&lcnt[d3 >> 8], 1);
    }
    __syncthreads();
    // scan 1024 counts (4/thread, shfl wave-scan); reserve global bucket space
    const int b4 = t * 4;
    int c0 = lcnt[b4], c1 = lcnt[b4 + 1], c2 = lcnt[b4 + 2], c3 = lcnt[b4 + 3];
    int s4 = c0 + c1 + c2 + c3;
    int v = s4;
#pragma unroll
    for (int off = 1; off < 64; off <<= 1) {
        int u = __shfl_up(v, off, 64);
        if (lane >= off) v += u;
    }
    if (lane == 63) wsum[w] = v;
    __syncthreads();
    int wbase = 0;
#pragma unroll
    for (int i = 0; i < 4; i++) wbase += (i < w) ? wsum[i] : 0;
    int run = wbase + v - s4;
    lscan[b4] = run;
    if (c0) lbase[b4] = b4 * BCAP + atomicAdd(&bcur[b4], c0);
    run += c0; lscan[b4 + 1] = run;
    if (c1) lbase[b4 + 1] = (b4 + 1) * BCAP + atomicAdd(&bcur[b4 + 1], c1);
    run += c1; lscan[b4 + 2] = run;
    if (c2) lbase[b4 + 2] = (b4 + 2) * BCAP + atomicAdd(&bcur[b4 + 2], c2);
    run += c2; lscan[b4 + 3] = run;
    if (c3) lbase[b4 + 3] = (b4 + 3) * BCAP + atomicAdd(&bcur[b4 + 3], c3);
    lcnt[b4] = 0; lcnt[b4 + 1] = 0; lcnt[b4 + 2] = 0; lcnt[b4 + 3] = 0;
    __syncthreads();
    // pass B: re-read (L2-hot), rank, stage (4 loads in flight)
    for (int base = 0; base < tcnt; base += 512) {
        int i0 = base + t, i1 = i0 + 256;
        bool v0 = i0 < tcnt, v1 = i1 < tcnt;
        int s0 = 0, d0 = 0, s1 = 0, d1 = 0;
        if (v0) { s0 = ei[tile0 + i0]; d0 = ei[E + tile0 + i0]; }
        if (v1) { s1 = ei[tile0 + i1]; d1 = ei[E + tile0 + i1]; }
        if (v0) {
            int b = d0 >> 8;
            int r = atomicAdd(&lcnt[b], 1);
            stage[lscan[b] + r] = make_int2(s0, d0);
        }
        if (v1) {
            int b = d1 >> 8;
            int r = atomicAdd(&lcnt[b], 1);
            stage[lscan[b] + r] = make_int2(s1, d1);
        }
    }
    __syncthreads();
    // contiguous-run copy out (~10.5-edge runs)
    for (int i = t; i < tcnt; i += 256) {
        int2 ed = stage[i];
        int b = ed.y >> 8;
        be[lbase[b] + (i - lscan[b])] = ed;
    }
}

// ---------------- L3: bucket counting sort -> csr, rp, re, dinv ----------------
__global__ __launch_bounds__(256) void sort_k(
        const int2* __restrict__ be, const int* __restrict__ bcur,
        int* __restrict__ csr, int* __restrict__ rp, int* __restrict__ re,
        float* __restrict__ dinv, int N) {
    __shared__ int lcnt[256];
    __shared__ int lscan[256];
    __shared__ int lc2[256];
    __shared__ int wsum[4];
    __shared__ int stage[BCAP];
    const int t = threadIdx.x;
    const int lane = t & 63, w = t >> 6;
    const int b = blockIdx.x;
    const int s = b * BCAP;
    int cnt = bcur[b]; if (cnt > BCAP) cnt = BCAP;
    lcnt[t] = 0; lc2[t] = 0;
    __syncthreads();
    // histogram (4 loads in flight)
    for (int base = 0; base < cnt; base += 1024) {
        int i0 = base + t;
        int y0 = -1, y1 = -1, y2 = -1, y3 = -1;
        if (i0       < cnt) y0 = be[s + i0].y;
        if (i0 + 256 < cnt) y1 = be[s + i0 + 256].y;
        if (i0 + 512 < cnt) y2 = be[s + i0 + 512].y;
        if (i0 + 768 < cnt) y3 = be[s + i0 + 768].y;
        if (y0 >= 0) atomicAdd(&lcnt[y0 & 255], 1);
        if (y1 >= 0) atomicAdd(&lcnt[y1 & 255], 1);
        if (y2 >= 0) atomicAdd(&lcnt[y2 & 255], 1);
        if (y3 >= 0) atomicAdd(&lcnt[y3 & 255], 1);
    }
    __syncthreads();
    int v = lcnt[t];
    int iv = v;
#pragma unroll
    for (int off = 1; off < 64; off <<= 1) {
        int u = __shfl_up(iv, off, 64);
        if (lane >= off) iv += u;
    }
    if (lane == 63) wsum[w] = iv;
    __syncthreads();
    int wbase = 0;
#pragma unroll
    for (int i = 0; i < 4; i++) wbase += (i < w) ? wsum[i] : 0;
    int excl = wbase + iv - v;
    lscan[t] = excl;
    int node = b * NPB + t;
    if (node < N) {
        rp[node] = s + excl;
        re[node] = s + excl + v;
        dinv[node] = rsqrtf((float)v + 1.0f);
    }
    __syncthreads();
    // rank + stage (2 loads in flight)
    for (int base = 0; base < cnt; base += 512) {
        int i0 = base + t, i1 = i0 + 256;
        bool v0 = i0 < cnt, v1 = i1 < cnt;
        int2 e0, e1;
        if (v0) e0 = be[s + i0];
        if (v1) e1 = be[s + i1];
        if (v0) {
            int d = e0.y & 255;
            int r = atomicAdd(&lc2[d], 1);
            stage[lscan[d] + r] = e0.x;
        }
        if (v1) {
            int d = e1.y & 255;
            int r = atomicAdd(&lc2[d], 1);
            stage[lscan[d] + r] = e1.x;
        }
    }
    __syncthreads();
    for (int i = t; i < cnt; i += 256) csr[s + i] = stage[i];
}

__device__ __forceinline__ void dec8(int2 r, float* f) {
    floatx2 a = __builtin_amdgcn_cvt_pk_f32_fp8(r.x, false);
    floatx2 b = __builtin_amdgcn_cvt_pk_f32_fp8(r.x, true);
    floatx2 c = __builtin_amdgcn_cvt_pk_f32_fp8(r.y, false);
    floatx2 d = __builtin_amdgcn_cvt_pk_f32_fp8(r.y, true);
    f[0] = a[0]; f[1] = a[1]; f[2] = b[0]; f[3] = b[1];
    f[4] = c[0]; f[5] = c[1]; f[6] = d[0]; f[7] = d[1];
}

// ---------------- L4: agg1 (fp8 gathers, rotate pipeline), epilogue -> zp = dinv*z ----
// 32 lanes/node, 8 nodes/block, 2 row-gathers in flight.
// acc accumulates sum(dinv_s*h_s) + dn*h_n; epilogue multiplies by dn inside relu arg.
__global__ __launch_bounds__(256) void agg1_k(const unsigned char* __restrict__ A,
                                              const int* __restrict__ rp,
                                              const int* __restrict__ re,
                                              const int* __restrict__ csr_src,
                                              const float* __restrict__ dinv,
                                              const float* __restrict__ b1,
                                              const float* __restrict__ w2o,
                                              float* __restrict__ zp, int N) {
    const int li = threadIdx.x & 31;
    const int node = blockIdx.x * 8 + (threadIdx.x >> 5);
    if (node >= N) return;
    const int eoff = (li & 15) * 8;
    const float dn = dinv[node];
    const int s0 = rp[node], s1 = re[node];
    float acc[8];
    {
        int2 raw = *(const int2*)(A + (size_t)node * DIM + eoff);
        float hv[8]; dec8(raw, hv);
        float w0 = (li < 16) ? dn : 0.f;    // self-loop weight (pre-dn factoring)
#pragma unroll
        for (int e = 0; e < 8; e++) acc[e] = hv[e] * w0;
    }
    for (int base = s0; base < s1; base += 32) {
        int sidx = 0; float dsl = 0.f;
        if (base + li < s1) { sidx = csr_src[base + li]; dsl = dinv[sidx]; }
        int nloc = s1 - base; if (nloc > 32) nloc = 32;
        int npair = (nloc + 1) >> 1;
        // rotate pipeline: gather for pair j+1 in flight while consuming pair j
        int sel = (li >> 4);
        int ssrc = __shfl(sidx, sel, 32);
        float wgt = __shfl(dsl, sel, 32);
        int2 hraw = *(const int2*)(A + (size_t)ssrc * DIM + eoff);
        for (int j = 1; j < npair; j++) {
            int sel1 = 2 * j + (li >> 4);
            int ssrc1 = __shfl(sidx, sel1, 32);
            float wgt1 = __shfl(dsl, sel1, 32);
            int2 hnext = *(const int2*)(A + (size_t)ssrc1 * DIM + eoff);
            float h[8]; dec8(hraw, h);
#pragma unroll
            for (int e = 0; e < 8; e++) acc[e] = fmaf(h[e], wgt, acc[e]);
            hraw = hnext; wgt = wgt1;
        }
        float h[8]; dec8(hraw, h);
#pragma unroll
        for (int e = 0; e < 8; e++) acc[e] = fmaf(h[e], wgt, acc[e]);
    }
#pragma unroll
    for (int e = 0; e < 8; e++) acc[e] += __shfl_xor(acc[e], 16, 32);
    float sum = 0.f;
    if (li < 16) {
        float4 b0 = *(const float4*)(b1 + eoff);
        float4 b3 = *(const float4*)(b1 + eoff + 4);
        float4 w0 = *(const float4*)(w2o + eoff);
        float4 w3 = *(const float4*)(w2o + eoff + 4);
        sum  = fmaxf(fmaf(dn, acc[0], b0.x), 0.f) * w0.x;
        sum += fmaxf(fmaf(dn, acc[1], b0.y), 0.f) * w0.y;
        sum += fmaxf(fmaf(dn, acc[2], b0.z), 0.f) * w0.z;
        sum += fmaxf(fmaf(dn, acc[3], b0.w), 0.f) * w0.w;
        sum += fmaxf(fmaf(dn, acc[4], b3.x), 0.f) * w3.x;
        sum += fmaxf(fmaf(dn, acc[5], b3.y), 0.f) * w3.y;
        sum += fmaxf(fmaf(dn, acc[6], b3.z), 0.f) * w3.z;
        sum += fmaxf(fmaf(dn, acc[7], b3.w), 0.f) * w3.w;
    }
#pragma unroll
    for (int off = 16; off > 0; off >>= 1) sum += __shfl_down(sum, off, 32);
    if (li == 0) zp[node] = dn * sum;    // zp = dinv * z
}

// ---------------- L5: final: out[n] = dn*(sum zp[s] + zp[n]) + c ----------------
__global__ void final_k(const float* __restrict__ zp, const float* __restrict__ dinv,
                        const int* __restrict__ rp, const int* __restrict__ re,
                        const int* __restrict__ csr_src,
                        const float* __restrict__ cbuf, float* __restrict__ out, int N) {
    int n = blockIdx.x * 256 + threadIdx.x;
    if (n >= N) return;
    float dn = dinv[n];
    int s0 = rp[n], s1 = re[n];
    float s = 0.f;
    int i = s0;
    for (; i + 4 <= s1; i += 4) {
        int x0 = csr_src[i], x1 = csr_src[i + 1], x2 = csr_src[i + 2], x3 = csr_src[i + 3];
        float z0 = zp[x0], z1 = zp[x1], z2 = zp[x2], z3 = zp[x3];
        s += (z0 + z1) + (z2 + z3);
    }
    for (; i < s1; i++) s += zp[csr_src[i]];
    out[n] = fmaf(dn, s + zp[n], cbuf[0]);
}

extern "C" void kernel_launch(void* const* d_in, const int* in_sizes, int n_in,
                              void* d_out, int out_size, void* d_ws, size_t ws_size,
                              hipStream_t stream) {
    const float* x  = (const float*)d_in[0];
    const int*   ei = (const int*)d_in[1];
    const float* W1 = (const float*)d_in[2];
    const float* b1 = (const float*)d_in[3];
    const float* W2 = (const float*)d_in[4];
    const float* b2 = (const float*)d_in[5];
    const float* Wo = (const float*)d_in[6];
    const float* bo = (const float*)d_in[7];
    float* out = (float*)d_out;

    const int N = in_sizes[0] / DIM;
    const int E = in_sizes[1] / 2;
    const int NB = (N + NPB - 1) >> 8;         // 256-node buckets
    const int ntiles = (E + T_SCAT - 1) / T_SCAT;
    const int ngemm = (N + 63) / 64;

    char* p = (char*)d_ws;
    auto alloc = [&](size_t bytes) {
        void* r = (void*)p;
        p += (bytes + 255) & ~size_t(255);
        return r;
    };
    unsigned char* A = (unsigned char*)alloc((size_t)N * DIM);          // 12.8 MB
    int2*  be     = (int2*)alloc((size_t)NB * BCAP * 8);                // 16 MB
    int*   csr    = (int*)alloc((size_t)NB * BCAP * 4);                 // 8 MB
    float* zp     = (float*)alloc((size_t)N * 4);
    float* dinv   = (float*)alloc((size_t)N * 4);
    float* w2o    = (float*)alloc(128 * 4);
    float* cbuf   = (float*)alloc(16);
    __half* w1frag= (__half*)alloc(2048 * 8 * 2);   // 32 KB
    int* rp       = (int*)alloc((size_t)N * 4);
    int* re       = (int*)alloc((size_t)N * 4);
    int* bcur     = (int*)alloc(1024 * 4);

    prep_k<<<10, 256, 0, stream>>>(W1, W2, Wo, b2, bo, w1frag, w2o, cbuf, bcur);
    scatter_gemm_k<<<ntiles + ngemm, 256, 0, stream>>>(ei, E, ntiles, be, bcur,
                                                       x, w1frag, A, N);
    sort_k<<<NB, 256, 0, stream>>>(be, bcur, csr, rp, re, dinv, N);
    agg1_k<<<(N + 7) / 8, 256, 0, stream>>>(A, rp, re, csr, dinv, b1, w2o, zp, N);
    final_k<<<(N + 255) / 256, 256, 0, stream>>>(zp, dinv, rp, re, csr, cbuf, out, N);
}